// Round 1
// baseline (4886.684 us; speedup 1.0000x reference)
//
#include <hip/hip_runtime.h>
#include <hip/hip_bf16.h>
#include <math.h>

#define B_   4
#define T_   2048
#define C_   1024
#define H_   8
#define DH   128
#define DFF  4096
#define M_   (B_*T_)   // 8192 rows

// ---------------------------------------------------------------------------
// LayerNorm: one block per row of C_=1024, 256 threads, 4 floats/thread.
// ---------------------------------------------------------------------------
__global__ __launch_bounds__(256) void ln_kernel(const float* __restrict__ in,
                                                 const float* __restrict__ g,
                                                 const float* __restrict__ bb,
                                                 float* __restrict__ out) {
  __shared__ float red[8];
  const int row = blockIdx.x;
  const int tid = threadIdx.x;
  const float* p = in + (size_t)row * C_;
  const float4 xv = *(const float4*)(p + (tid << 2));
  float s  = xv.x + xv.y + xv.z + xv.w;
  float sq = xv.x*xv.x + xv.y*xv.y + xv.z*xv.z + xv.w*xv.w;
  #pragma unroll
  for (int off = 32; off > 0; off >>= 1) {
    s  += __shfl_xor(s, off);
    sq += __shfl_xor(sq, off);
  }
  if ((tid & 63) == 0) { red[(tid >> 6) * 2] = s; red[(tid >> 6) * 2 + 1] = sq; }
  __syncthreads();
  s  = red[0] + red[2] + red[4] + red[6];
  sq = red[1] + red[3] + red[5] + red[7];
  const float mu  = s * (1.0f / C_);
  const float var = sq * (1.0f / C_) - mu * mu;
  const float rs  = rsqrtf(var + 1e-5f);
  const float4 gv = *(const float4*)(g  + (tid << 2));
  const float4 bv = *(const float4*)(bb + (tid << 2));
  float4 ov;
  ov.x = (xv.x - mu) * rs * gv.x + bv.x;
  ov.y = (xv.y - mu) * rs * gv.y + bv.y;
  ov.z = (xv.z - mu) * rs * gv.z + bv.z;
  ov.w = (xv.w - mu) * rs * gv.w + bv.w;
  *(float4*)(out + (size_t)row * C_ + (tid << 2)) = ov;
}

// ---------------------------------------------------------------------------
// fp32 GEMM core: 64x64 tile, BK=16, 256 threads, 4x4 micro-tile per thread.
// A: row-major MxK (pre-offset to tile row), B: row-major KxN (pre-offset to
// tile col). As stored [k][m] (transposed), Bs stored [k][n].
// ---------------------------------------------------------------------------
__device__ __forceinline__ void gemm64_core(const float* __restrict__ A, int lda,
                                            const float* __restrict__ B, int ldb,
                                            int K, float acc[4][4],
                                            float (*As)[64], float (*Bs)[64]) {
  const int tid = threadIdx.x;
  const int ar = tid >> 2, ak = (tid & 3) << 2;    // A stage: row, k-quad
  const int bk = tid >> 4, bn = (tid & 15) << 2;   // B stage: k, n-quad
  const int tx = tid & 15, ty = tid >> 4;          // compute: 16x16 thread grid
  for (int k0 = 0; k0 < K; k0 += 16) {
    const float4 av = *(const float4*)(A + (size_t)ar * lda + k0 + ak);
    const float4 bv = *(const float4*)(B + (size_t)(k0 + bk) * ldb + bn);
    __syncthreads();   // previous compute done reading LDS
    As[ak + 0][ar] = av.x; As[ak + 1][ar] = av.y;
    As[ak + 2][ar] = av.z; As[ak + 3][ar] = av.w;
    *(float4*)(&Bs[bk][bn]) = bv;
    __syncthreads();
    #pragma unroll
    for (int kk = 0; kk < 16; ++kk) {
      const float4 a4 = *(const float4*)(&As[kk][ty << 2]);
      const float4 b4 = *(const float4*)(&Bs[kk][tx << 2]);
      const float a[4] = {a4.x, a4.y, a4.z, a4.w};
      const float b[4] = {b4.x, b4.y, b4.z, b4.w};
      #pragma unroll
      for (int i = 0; i < 4; ++i)
        #pragma unroll
        for (int j = 0; j < 4; ++j)
          acc[i][j] = fmaf(a[i], b[j], acc[i][j]);
    }
  }
}

// ---------------------------------------------------------------------------
// QKV projection: q/k/v[b][h][t][d] = sum_c h[b*T+t][c] * w{q,k,v}[h][c][d]
// grid = (Dh/64=2, M/64=128, 3*H=24)
// ---------------------------------------------------------------------------
__global__ __launch_bounds__(256) void qkv_kernel(const float* __restrict__ h,
                                                  const float* __restrict__ wq,
                                                  const float* __restrict__ wk,
                                                  const float* __restrict__ wv,
                                                  float* __restrict__ qkv) {
  __shared__ float As[16][64];
  __shared__ float Bs[16][64];
  const int n0 = blockIdx.x << 6;
  const int m0 = blockIdx.y << 6;
  const int z  = blockIdx.z;
  const int w = z >> 3, head = z & 7;
  const float* W = (w == 0 ? wq : (w == 1 ? wk : wv)) + (size_t)head * C_ * DH;
  float acc[4][4] = {{0.f}};
  gemm64_core(h + (size_t)m0 * C_, C_, W + n0, DH, C_, acc, As, Bs);
  const int tx = threadIdx.x & 15, ty = threadIdx.x >> 4;
  float* outw = qkv + (size_t)w * M_ * C_;   // each of q,k,v is B*H*T*DH = M_*C_
  #pragma unroll
  for (int i = 0; i < 4; ++i) {
    const int m = m0 + (ty << 2) + i;
    const int b = m >> 11, t = m & (T_ - 1);
    float* orow = outw + ((size_t)(b * H_ + head) * T_ + t) * DH + n0 + (tx << 2);
    *(float4*)orow = make_float4(acc[i][0], acc[i][1], acc[i][2], acc[i][3]);
  }
}

// ---------------------------------------------------------------------------
// Flash attention (fp32, non-causal), scores *= sqrt(Dh) (faithful).
// One block = 32 queries of one (b,h); loop over 32-key tiles, online softmax.
// Epilogue writes xo = x + attn_out directly (concat-head layout).
// grid = (T/32=64, B*H=32), 256 threads: tx=d-lane(8), ty=query-row(32).
// ---------------------------------------------------------------------------
__global__ __launch_bounds__(256) void attn_kernel(const float* __restrict__ q,
                                                   const float* __restrict__ k,
                                                   const float* __restrict__ v,
                                                   const float* __restrict__ x,
                                                   float* __restrict__ xo) {
  __shared__ float Qs[DH][32];   // transposed: [d][row]
  __shared__ float Ks[DH][32];   // transposed: [d][col]
  __shared__ float Vs[32][DH];
  __shared__ float Ps[32][36];   // padded stride 36: conflict-free row reads
  const int bh  = blockIdx.y;
  const int qt0 = blockIdx.x << 5;
  const size_t base = (size_t)bh * T_ * DH;
  const float* qb = q + base;
  const float* kb = k + base;
  const float* vb = v + base;
  const int tid = threadIdx.x;
  const int tx = tid & 7, ty = tid >> 3;
  const int sr = tid >> 3, sd = (tid & 7) << 4;   // staging: row, 16-wide d slab
  #pragma unroll
  for (int i = 0; i < 16; i += 4) {
    const float4 t4 = *(const float4*)(qb + (size_t)(qt0 + sr) * DH + sd + i);
    Qs[sd + i + 0][sr] = t4.x; Qs[sd + i + 1][sr] = t4.y;
    Qs[sd + i + 2][sr] = t4.z; Qs[sd + i + 3][sr] = t4.w;
  }
  float O[16];
  #pragma unroll
  for (int i = 0; i < 16; ++i) O[i] = 0.f;
  float m_i = -1e30f, l_i = 0.f;

  for (int kt = 0; kt < T_; kt += 32) {
    __syncthreads();   // prior PV reads done before restaging
    #pragma unroll
    for (int i = 0; i < 16; i += 4) {
      const float4 kt4 = *(const float4*)(kb + (size_t)(kt + sr) * DH + sd + i);
      Ks[sd + i + 0][sr] = kt4.x; Ks[sd + i + 1][sr] = kt4.y;
      Ks[sd + i + 2][sr] = kt4.z; Ks[sd + i + 3][sr] = kt4.w;
      const float4 vt4 = *(const float4*)(vb + (size_t)(kt + sr) * DH + sd + i);
      *(float4*)(&Vs[sr][sd + i]) = vt4;
    }
    __syncthreads();
    // S = Q K^T for this tile: thread does row ty, cols tx*4..tx*4+3
    float s0 = 0.f, s1 = 0.f, s2 = 0.f, s3 = 0.f;
    #pragma unroll 8
    for (int d = 0; d < DH; ++d) {
      const float qv = Qs[d][ty];
      const float4 kv = *(const float4*)(&Ks[d][tx << 2]);
      s0 = fmaf(qv, kv.x, s0); s1 = fmaf(qv, kv.y, s1);
      s2 = fmaf(qv, kv.z, s2); s3 = fmaf(qv, kv.w, s3);
    }
    const float sc = 11.313708498984761f;   // * sqrt(Dh), faithful to ref
    s0 *= sc; s1 *= sc; s2 *= sc; s3 *= sc;
    float mloc = fmaxf(fmaxf(s0, s1), fmaxf(s2, s3));
    #pragma unroll
    for (int off = 1; off < 8; off <<= 1) mloc = fmaxf(mloc, __shfl_xor(mloc, off));
    const float m_new = fmaxf(m_i, mloc);
    const float p0 = __expf(s0 - m_new), p1 = __expf(s1 - m_new);
    const float p2 = __expf(s2 - m_new), p3 = __expf(s3 - m_new);
    float psum = p0 + p1 + p2 + p3;
    #pragma unroll
    for (int off = 1; off < 8; off <<= 1) psum += __shfl_xor(psum, off);
    const float alpha = __expf(m_i - m_new);
    l_i = l_i * alpha + psum;
    m_i = m_new;
    #pragma unroll
    for (int i = 0; i < 16; ++i) O[i] *= alpha;
    *(float4*)(&Ps[ty][tx << 2]) = make_float4(p0, p1, p2, p3);
    __syncthreads();
    // O += P V : thread owns cols d = tx + 8*i (strided, conflict-free Vs reads)
    #pragma unroll 4
    for (int j = 0; j < 32; ++j) {
      const float p = Ps[ty][j];
      #pragma unroll
      for (int i = 0; i < 16; ++i)
        O[i] = fmaf(p, Vs[j][tx + (i << 3)], O[i]);
    }
  }
  const float inv_l = 1.0f / l_i;
  const int b  = bh >> 3, hh = bh & 7;
  const int t  = qt0 + ty;
  const size_t xrow = ((size_t)(b * T_ + t)) * C_ + (size_t)hh * DH;
  #pragma unroll
  for (int i = 0; i < 16; ++i) {
    const int d = tx + (i << 3);
    xo[xrow + d] = x[xrow + d] + O[i] * inv_l;
  }
}

// ---------------------------------------------------------------------------
// FF1: ff1 = relu(h2 @ w1 + b1)    grid = (Dff/64=64, M/64=128)
// ---------------------------------------------------------------------------
__global__ __launch_bounds__(256) void ff1_kernel(const float* __restrict__ h2,
                                                  const float* __restrict__ w1,
                                                  const float* __restrict__ b1,
                                                  float* __restrict__ ff1) {
  __shared__ float As[16][64];
  __shared__ float Bs[16][64];
  const int n0 = blockIdx.x << 6;
  const int m0 = blockIdx.y << 6;
  float acc[4][4] = {{0.f}};
  gemm64_core(h2 + (size_t)m0 * C_, C_, w1 + n0, DFF, C_, acc, As, Bs);
  const int tx = threadIdx.x & 15, ty = threadIdx.x >> 4;
  #pragma unroll
  for (int i = 0; i < 4; ++i) {
    const int m = m0 + (ty << 2) + i;
    const int n = n0 + (tx << 2);
    const float4 bias = *(const float4*)(b1 + n);
    float4 o;
    o.x = fmaxf(acc[i][0] + bias.x, 0.f);
    o.y = fmaxf(acc[i][1] + bias.y, 0.f);
    o.z = fmaxf(acc[i][2] + bias.z, 0.f);
    o.w = fmaxf(acc[i][3] + bias.w, 0.f);
    *(float4*)(ff1 + (size_t)m * DFF + n) = o;
  }
}

// ---------------------------------------------------------------------------
// FF2: out = ff1 @ w2 + b2 + xo    grid = (C/64=16, M/64=128)
// ---------------------------------------------------------------------------
__global__ __launch_bounds__(256) void ff2_kernel(const float* __restrict__ ff1,
                                                  const float* __restrict__ w2,
                                                  const float* __restrict__ b2,
                                                  const float* __restrict__ xo,
                                                  float* __restrict__ out) {
  __shared__ float As[16][64];
  __shared__ float Bs[16][64];
  const int n0 = blockIdx.x << 6;
  const int m0 = blockIdx.y << 6;
  float acc[4][4] = {{0.f}};
  gemm64_core(ff1 + (size_t)m0 * DFF, DFF, w2 + n0, C_, DFF, acc, As, Bs);
  const int tx = threadIdx.x & 15, ty = threadIdx.x >> 4;
  #pragma unroll
  for (int i = 0; i < 4; ++i) {
    const int m = m0 + (ty << 2) + i;
    const int n = n0 + (tx << 2);
    const float4 bias = *(const float4*)(b2 + n);
    const float4 r = *(const float4*)(xo + (size_t)m * C_ + n);
    float4 o;
    o.x = acc[i][0] + bias.x + r.x;
    o.y = acc[i][1] + bias.y + r.y;
    o.z = acc[i][2] + bias.z + r.z;
    o.w = acc[i][3] + bias.w + r.w;
    *(float4*)(out + (size_t)m * C_ + n) = o;
  }
}

// ---------------------------------------------------------------------------
// Workspace layout (floats):
//   [0,      MC)   xo  (x + attn_out)          32 MB
//   [MC,    2MC)   h / h2 (LN outputs)         32 MB
//   [2MC,   5MC)   q,k,v  (B,H,T,Dh each)      96 MB
//   [2MC,   2MC+M*DFF)  ff1 (reuses dead qkv) 128 MB
// total required: 192 MB
// ---------------------------------------------------------------------------
extern "C" void kernel_launch(void* const* d_in, const int* in_sizes, int n_in,
                              void* d_out, int out_size, void* d_ws, size_t ws_size,
                              hipStream_t stream) {
  (void)in_sizes; (void)n_in; (void)out_size; (void)ws_size;
  const float* x     = (const float*)d_in[0];
  const float* wq    = (const float*)d_in[1];
  const float* wk    = (const float*)d_in[2];
  const float* wv    = (const float*)d_in[3];
  const float* w1    = (const float*)d_in[4];
  const float* b1    = (const float*)d_in[5];
  const float* w2    = (const float*)d_in[6];
  const float* b2    = (const float*)d_in[7];
  const float* ln1_g = (const float*)d_in[8];
  const float* ln1_b = (const float*)d_in[9];
  const float* ln2_g = (const float*)d_in[10];
  const float* ln2_b = (const float*)d_in[11];
  float* out = (float*)d_out;

  const size_t MC = (size_t)M_ * C_;
  float* ws  = (float*)d_ws;
  float* xo  = ws;
  float* h   = ws + MC;
  float* qkv = ws + 2 * MC;
  float* ff1 = qkv;              // reuses q/k/v region after attention

  ln_kernel<<<M_, 256, 0, stream>>>(x, ln1_g, ln1_b, h);
  qkv_kernel<<<dim3(DH / 64, M_ / 64, 3 * H_), 256, 0, stream>>>(h, wq, wk, wv, qkv);
  attn_kernel<<<dim3(T_ / 32, B_ * H_), 256, 0, stream>>>(qkv, qkv + MC, qkv + 2 * MC,
                                                          x, xo);
  ln_kernel<<<M_, 256, 0, stream>>>(xo, ln2_g, ln2_b, h);
  ff1_kernel<<<dim3(DFF / 64, M_ / 64), 256, 0, stream>>>(h, w1, b1, ff1);
  ff2_kernel<<<dim3(C_ / 64, M_ / 64), 256, 0, stream>>>(ff1, w2, b2, xo, out);
}

// Round 2
// 2885.306 us; speedup vs baseline: 1.6936x; 1.6936x over previous
//
#include <hip/hip_runtime.h>
#include <hip/hip_bf16.h>
#include <math.h>

#define B_   4
#define T_   2048
#define C_   1024
#define H_   8
#define DH   128
#define DFF  4096
#define M_   (B_*T_)   // 8192 rows

typedef __attribute__((ext_vector_type(8))) short bf16x8;
typedef __attribute__((ext_vector_type(4))) float f32x4;

__device__ __forceinline__ unsigned short f2bf(float x) {
  union { float f; unsigned u; } v; v.f = x;
  return (unsigned short)((v.u + 0x7fffu + ((v.u >> 16) & 1u)) >> 16);
}
__device__ __forceinline__ float bf2f(unsigned short h) {
  union { unsigned u; float f; } v; v.u = ((unsigned)h) << 16; return v.f;
}

// ---------------------------------------------------------------------------
// LayerNorm: one block per row of C_=1024, 256 threads, 4 floats/thread.
// ---------------------------------------------------------------------------
__global__ __launch_bounds__(256) void ln_kernel(const float* __restrict__ in,
                                                 const float* __restrict__ g,
                                                 const float* __restrict__ bb,
                                                 float* __restrict__ out) {
  __shared__ float red[8];
  const int row = blockIdx.x;
  const int tid = threadIdx.x;
  const float* p = in + (size_t)row * C_;
  const float4 xv = *(const float4*)(p + (tid << 2));
  float s  = xv.x + xv.y + xv.z + xv.w;
  float sq = xv.x*xv.x + xv.y*xv.y + xv.z*xv.z + xv.w*xv.w;
  #pragma unroll
  for (int off = 32; off > 0; off >>= 1) {
    s  += __shfl_xor(s, off);
    sq += __shfl_xor(sq, off);
  }
  if ((tid & 63) == 0) { red[(tid >> 6) * 2] = s; red[(tid >> 6) * 2 + 1] = sq; }
  __syncthreads();
  s  = red[0] + red[2] + red[4] + red[6];
  sq = red[1] + red[3] + red[5] + red[7];
  const float mu  = s * (1.0f / C_);
  const float var = sq * (1.0f / C_) - mu * mu;
  const float rs  = rsqrtf(var + 1e-5f);
  const float4 gv = *(const float4*)(g  + (tid << 2));
  const float4 bv = *(const float4*)(bb + (tid << 2));
  float4 ov;
  ov.x = (xv.x - mu) * rs * gv.x + bv.x;
  ov.y = (xv.y - mu) * rs * gv.y + bv.y;
  ov.z = (xv.z - mu) * rs * gv.z + bv.z;
  ov.w = (xv.w - mu) * rs * gv.w + bv.w;
  *(float4*)(out + (size_t)row * C_ + (tid << 2)) = ov;
}

// ---------------------------------------------------------------------------
// fp32 GEMM core: 64x64 tile, BK=16, 256 threads, 4x4 micro-tile per thread.
// ---------------------------------------------------------------------------
__device__ __forceinline__ void gemm64_core(const float* __restrict__ A, int lda,
                                            const float* __restrict__ B, int ldb,
                                            int K, float acc[4][4],
                                            float (*As)[64], float (*Bs)[64]) {
  const int tid = threadIdx.x;
  const int ar = tid >> 2, ak = (tid & 3) << 2;
  const int bk = tid >> 4, bn = (tid & 15) << 2;
  const int tx = tid & 15, ty = tid >> 4;
  for (int k0 = 0; k0 < K; k0 += 16) {
    const float4 av = *(const float4*)(A + (size_t)ar * lda + k0 + ak);
    const float4 bv = *(const float4*)(B + (size_t)(k0 + bk) * ldb + bn);
    __syncthreads();
    As[ak + 0][ar] = av.x; As[ak + 1][ar] = av.y;
    As[ak + 2][ar] = av.z; As[ak + 3][ar] = av.w;
    *(float4*)(&Bs[bk][bn]) = bv;
    __syncthreads();
    #pragma unroll
    for (int kk = 0; kk < 16; ++kk) {
      const float4 a4 = *(const float4*)(&As[kk][ty << 2]);
      const float4 b4 = *(const float4*)(&Bs[kk][tx << 2]);
      const float a[4] = {a4.x, a4.y, a4.z, a4.w};
      const float b[4] = {b4.x, b4.y, b4.z, b4.w};
      #pragma unroll
      for (int i = 0; i < 4; ++i)
        #pragma unroll
        for (int j = 0; j < 4; ++j)
          acc[i][j] = fmaf(a[i], b[j], acc[i][j]);
    }
  }
}

// ---------------------------------------------------------------------------
// QKV projection. q,k written [bh][t][d]; v written TRANSPOSED [bh][d][t]
// (so the attention kernel can stage V^T with packed conflict-free writes).
// grid = (Dh/64=2, M/64=128, 3*H=24)
// ---------------------------------------------------------------------------
__global__ __launch_bounds__(256) void qkv_kernel(const float* __restrict__ h,
                                                  const float* __restrict__ wq,
                                                  const float* __restrict__ wk,
                                                  const float* __restrict__ wv,
                                                  float* __restrict__ qkv) {
  __shared__ float As[16][64];
  __shared__ float Bs[16][64];
  const int n0 = blockIdx.x << 6;
  const int m0 = blockIdx.y << 6;
  const int z  = blockIdx.z;
  const int w = z >> 3, head = z & 7;
  const float* W = (w == 0 ? wq : (w == 1 ? wk : wv)) + (size_t)head * C_ * DH;
  float acc[4][4] = {{0.f}};
  gemm64_core(h + (size_t)m0 * C_, C_, W + n0, DH, C_, acc, As, Bs);
  const int tx = threadIdx.x & 15, ty = threadIdx.x >> 4;
  float* outw = qkv + (size_t)w * M_ * C_;
  if (w < 2) {
    #pragma unroll
    for (int i = 0; i < 4; ++i) {
      const int m = m0 + (ty << 2) + i;
      const int b = m >> 11, t = m & (T_ - 1);
      float* orow = outw + ((size_t)(b * H_ + head) * T_ + t) * DH + n0 + (tx << 2);
      *(float4*)orow = make_float4(acc[i][0], acc[i][1], acc[i][2], acc[i][3]);
    }
  } else {
    // v transposed: [bh][d][t]
    const int m = m0 + (ty << 2);
    const int b = m >> 11, t0 = m & (T_ - 1);
    #pragma unroll
    for (int j = 0; j < 4; ++j) {
      const int d = n0 + (tx << 2) + j;
      float* oc = outw + ((size_t)(b * H_ + head) * DH + d) * T_ + t0;
      *(float4*)oc = make_float4(acc[0][j], acc[1][j], acc[2][j], acc[3][j]);
    }
  }
}

// ---------------------------------------------------------------------------
// MFMA flash attention, split-bf16 QK^T (qh*kh + qh*kl + ql*kh), bf16 PV.
// BQ=128 (4 waves x 32 q-rows, Q frags in registers), BK=32 keys/tile.
// scores *= sqrt(Dh) (faithful). Epilogue: xo = x + softmax(S) V.
// grid = (T/128=16, B*H=32), 256 threads.
// ---------------------------------------------------------------------------
#define BQ   128
#define BK   32
#define KSTR 136   // K LDS row stride in ushorts (d-dim 128 + 8 pad)
#define VSTR 40    // Vt / P LDS row stride in ushorts (key-dim 32 + 8 pad)

__device__ __forceinline__ f32x4 mfma_bf16(bf16x8 a, bf16x8 b, f32x4 c) {
  return __builtin_amdgcn_mfma_f32_16x16x32_bf16(a, b, c, 0, 0, 0);
}

__global__ __launch_bounds__(256, 2) void attn_kernel(const float* __restrict__ q,
                                                      const float* __restrict__ k,
                                                      const float* __restrict__ vt,
                                                      const float* __restrict__ x,
                                                      float* __restrict__ xo) {
  __shared__ __align__(16) unsigned short KhS[BK * KSTR];
  __shared__ __align__(16) unsigned short KlS[BK * KSTR];
  __shared__ __align__(16) unsigned short VtS[DH * VSTR];
  __shared__ __align__(16) unsigned short PS [BQ * VSTR];

  const int bh  = blockIdx.y;
  const int qt0 = blockIdx.x * BQ;
  const int tid  = threadIdx.x;
  const int w    = tid >> 6;
  const int lane = tid & 63;
  const int l15  = lane & 15;
  const int quad = lane >> 4;

  const float* qb = q  + (size_t)bh * T_ * DH;   // [t][d]
  const float* kb = k  + (size_t)bh * T_ * DH;   // [t][d]
  const float* vb = vt + (size_t)bh * DH * T_;   // [d][t]

  // ---- Q fragments (hi/lo), 2 row-tiles x 4 k-chunks, in registers ----
  bf16x8 Qh[2][4], Ql[2][4];
  #pragma unroll
  for (int rt = 0; rt < 2; ++rt) {
    const int row = qt0 + w * 32 + rt * 16 + l15;
    #pragma unroll
    for (int kc = 0; kc < 4; ++kc) {
      const float* p = qb + (size_t)row * DH + kc * 32 + quad * 8;
      const float4 a = *(const float4*)p;
      const float4 b = *(const float4*)(p + 4);
      const float xs[8] = {a.x, a.y, a.z, a.w, b.x, b.y, b.z, b.w};
      bf16x8 hv, lv;
      #pragma unroll
      for (int j = 0; j < 8; ++j) {
        const unsigned short hb = f2bf(xs[j]);
        hv[j] = (short)hb;
        lv[j] = (short)f2bf(xs[j] - bf2f(hb));
      }
      Qh[rt][kc] = hv; Ql[rt][kc] = lv;
    }
  }

  f32x4 O[2][8];
  #pragma unroll
  for (int rt = 0; rt < 2; ++rt)
    #pragma unroll
    for (int n = 0; n < 8; ++n)
      #pragma unroll
      for (int r = 0; r < 4; ++r) O[rt][n][r] = 0.f;
  float m_i[2][4], l_i[2][4];
  #pragma unroll
  for (int rt = 0; rt < 2; ++rt)
    #pragma unroll
    for (int r = 0; r < 4; ++r) { m_i[rt][r] = -1e30f; l_i[rt][r] = 0.f; }

  const float sc = 11.313708498984761f;   // sqrt(128), faithful to ref

  for (int kt = 0; kt < T_; kt += BK) {
    __syncthreads();   // previous iteration's LDS reads complete
    // ---- stage K tile as hi/lo bf16 (32 keys x 128 d) ----
    #pragma unroll
    for (int i = 0; i < 4; ++i) {
      const int f = i * 256 + tid;
      const int key = f >> 5, d4 = (f & 31) << 2;
      const float4 kv = *(const float4*)(kb + (size_t)(kt + key) * DH + d4);
      const float xs[4] = {kv.x, kv.y, kv.z, kv.w};
      unsigned short hh[4], ll[4];
      #pragma unroll
      for (int j = 0; j < 4; ++j) {
        hh[j] = f2bf(xs[j]);
        ll[j] = f2bf(xs[j] - bf2f(hh[j]));
      }
      uint2 hp, lp;
      hp.x = (unsigned)hh[0] | ((unsigned)hh[1] << 16);
      hp.y = (unsigned)hh[2] | ((unsigned)hh[3] << 16);
      lp.x = (unsigned)ll[0] | ((unsigned)ll[1] << 16);
      lp.y = (unsigned)ll[2] | ((unsigned)ll[3] << 16);
      *(uint2*)&KhS[key * KSTR + d4] = hp;
      *(uint2*)&KlS[key * KSTR + d4] = lp;
    }
    // ---- stage V^T tile (128 d x 32 keys), packed along key ----
    #pragma unroll
    for (int i = 0; i < 4; ++i) {
      const int f = i * 256 + tid;
      const int d = f >> 3, k4 = (f & 7) << 2;
      const float4 vv = *(const float4*)(vb + (size_t)d * T_ + kt + k4);
      uint2 vp;
      vp.x = (unsigned)f2bf(vv.x) | ((unsigned)f2bf(vv.y) << 16);
      vp.y = (unsigned)f2bf(vv.z) | ((unsigned)f2bf(vv.w) << 16);
      *(uint2*)&VtS[d * VSTR + k4] = vp;
    }
    __syncthreads();

    // ---- S = Q K^T (split precision, 3 MFMAs per tile-pair) ----
    f32x4 S[2][2];
    #pragma unroll
    for (int rt = 0; rt < 2; ++rt)
      #pragma unroll
      for (int ct = 0; ct < 2; ++ct)
        #pragma unroll
        for (int r = 0; r < 4; ++r) S[rt][ct][r] = 0.f;
    #pragma unroll
    for (int kc = 0; kc < 4; ++kc) {
      const int off = kc * 32 + quad * 8;
      const bf16x8 bh0 = *(const bf16x8*)&KhS[(l15)      * KSTR + off];
      const bf16x8 bh1 = *(const bf16x8*)&KhS[(16 + l15) * KSTR + off];
      const bf16x8 bl0 = *(const bf16x8*)&KlS[(l15)      * KSTR + off];
      const bf16x8 bl1 = *(const bf16x8*)&KlS[(16 + l15) * KSTR + off];
      #pragma unroll
      for (int rt = 0; rt < 2; ++rt) {
        S[rt][0] = mfma_bf16(Ql[rt][kc], bh0, S[rt][0]);
        S[rt][0] = mfma_bf16(Qh[rt][kc], bl0, S[rt][0]);
        S[rt][0] = mfma_bf16(Qh[rt][kc], bh0, S[rt][0]);
        S[rt][1] = mfma_bf16(Ql[rt][kc], bh1, S[rt][1]);
        S[rt][1] = mfma_bf16(Qh[rt][kc], bl1, S[rt][1]);
        S[rt][1] = mfma_bf16(Qh[rt][kc], bh1, S[rt][1]);
      }
    }

    // ---- online softmax (rows = quad*4+r, cols = ct*16+l15) ----
    #pragma unroll
    for (int rt = 0; rt < 2; ++rt) {
      #pragma unroll
      for (int r = 0; r < 4; ++r) {
        const float s0 = S[rt][0][r] * sc;
        const float s1 = S[rt][1][r] * sc;
        float mx = fmaxf(s0, s1);
        #pragma unroll
        for (int msk = 1; msk < 16; msk <<= 1) mx = fmaxf(mx, __shfl_xor(mx, msk));
        const float m_new = fmaxf(m_i[rt][r], mx);
        const float alpha = __expf(m_i[rt][r] - m_new);
        m_i[rt][r] = m_new;
        const float p0 = __expf(s0 - m_new);
        const float p1 = __expf(s1 - m_new);
        float rs = p0 + p1;
        #pragma unroll
        for (int msk = 1; msk < 16; msk <<= 1) rs += __shfl_xor(rs, msk);
        l_i[rt][r] = l_i[rt][r] * alpha + rs;
        #pragma unroll
        for (int n = 0; n < 8; ++n) O[rt][n][r] *= alpha;
        const int prow = w * 32 + rt * 16 + quad * 4 + r;
        PS[prow * VSTR + l15]      = f2bf(p0);
        PS[prow * VSTR + 16 + l15] = f2bf(p1);
      }
    }
    __syncthreads();

    // ---- O += P V ----
    bf16x8 aP[2];
    #pragma unroll
    for (int rt = 0; rt < 2; ++rt)
      aP[rt] = *(const bf16x8*)&PS[(w * 32 + rt * 16 + l15) * VSTR + quad * 8];
    #pragma unroll
    for (int n = 0; n < 8; ++n) {
      const bf16x8 bv = *(const bf16x8*)&VtS[(n * 16 + l15) * VSTR + quad * 8];
      O[0][n] = mfma_bf16(aP[0], bv, O[0][n]);
      O[1][n] = mfma_bf16(aP[1], bv, O[1][n]);
    }
  }

  // ---- epilogue: xo = x + O / l ----
  const int b = bh >> 3, hh = bh & 7;
  #pragma unroll
  for (int rt = 0; rt < 2; ++rt) {
    #pragma unroll
    for (int r = 0; r < 4; ++r) {
      const float inv_l = 1.0f / l_i[rt][r];
      const int t = qt0 + w * 32 + rt * 16 + quad * 4 + r;
      const size_t xrow = ((size_t)(b * T_ + t)) * C_ + (size_t)hh * DH;
      #pragma unroll
      for (int n = 0; n < 8; ++n) {
        const int d = n * 16 + l15;
        xo[xrow + d] = x[xrow + d] + O[rt][n][r] * inv_l;
      }
    }
  }
}

// ---------------------------------------------------------------------------
// FF1: ff1 = relu(h2 @ w1 + b1)    grid = (Dff/64=64, M/64=128)
// ---------------------------------------------------------------------------
__global__ __launch_bounds__(256) void ff1_kernel(const float* __restrict__ h2,
                                                  const float* __restrict__ w1,
                                                  const float* __restrict__ b1,
                                                  float* __restrict__ ff1) {
  __shared__ float As[16][64];
  __shared__ float Bs[16][64];
  const int n0 = blockIdx.x << 6;
  const int m0 = blockIdx.y << 6;
  float acc[4][4] = {{0.f}};
  gemm64_core(h2 + (size_t)m0 * C_, C_, w1 + n0, DFF, C_, acc, As, Bs);
  const int tx = threadIdx.x & 15, ty = threadIdx.x >> 4;
  #pragma unroll
  for (int i = 0; i < 4; ++i) {
    const int m = m0 + (ty << 2) + i;
    const int n = n0 + (tx << 2);
    const float4 bias = *(const float4*)(b1 + n);
    float4 o;
    o.x = fmaxf(acc[i][0] + bias.x, 0.f);
    o.y = fmaxf(acc[i][1] + bias.y, 0.f);
    o.z = fmaxf(acc[i][2] + bias.z, 0.f);
    o.w = fmaxf(acc[i][3] + bias.w, 0.f);
    *(float4*)(ff1 + (size_t)m * DFF + n) = o;
  }
}

// ---------------------------------------------------------------------------
// FF2: out = ff1 @ w2 + b2 + xo    grid = (C/64=16, M/64=128)
// ---------------------------------------------------------------------------
__global__ __launch_bounds__(256) void ff2_kernel(const float* __restrict__ ff1,
                                                  const float* __restrict__ w2,
                                                  const float* __restrict__ b2,
                                                  const float* __restrict__ xo,
                                                  float* __restrict__ out) {
  __shared__ float As[16][64];
  __shared__ float Bs[16][64];
  const int n0 = blockIdx.x << 6;
  const int m0 = blockIdx.y << 6;
  float acc[4][4] = {{0.f}};
  gemm64_core(ff1 + (size_t)m0 * DFF, DFF, w2 + n0, C_, DFF, acc, As, Bs);
  const int tx = threadIdx.x & 15, ty = threadIdx.x >> 4;
  #pragma unroll
  for (int i = 0; i < 4; ++i) {
    const int m = m0 + (ty << 2) + i;
    const int n = n0 + (tx << 2);
    const float4 bias = *(const float4*)(b2 + n);
    const float4 r = *(const float4*)(xo + (size_t)m * C_ + n);
    float4 o;
    o.x = acc[i][0] + bias.x + r.x;
    o.y = acc[i][1] + bias.y + r.y;
    o.z = acc[i][2] + bias.z + r.z;
    o.w = acc[i][3] + bias.w + r.w;
    *(float4*)(out + (size_t)m * C_ + n) = o;
  }
}

// ---------------------------------------------------------------------------
// Workspace layout (floats):
//   [0,      MC)   xo  (x + attn_out)          32 MB
//   [MC,    2MC)   h / h2 (LN outputs)         32 MB
//   [2MC,   5MC)   q,k,v  (q,k: [bh][t][d]; v: [bh][d][t])  96 MB
//   [2MC,   2MC+M*DFF)  ff1 (reuses dead qkv) 128 MB
// ---------------------------------------------------------------------------
extern "C" void kernel_launch(void* const* d_in, const int* in_sizes, int n_in,
                              void* d_out, int out_size, void* d_ws, size_t ws_size,
                              hipStream_t stream) {
  (void)in_sizes; (void)n_in; (void)out_size; (void)ws_size;
  const float* x     = (const float*)d_in[0];
  const float* wq    = (const float*)d_in[1];
  const float* wk    = (const float*)d_in[2];
  const float* wv    = (const float*)d_in[3];
  const float* w1    = (const float*)d_in[4];
  const float* b1    = (const float*)d_in[5];
  const float* w2    = (const float*)d_in[6];
  const float* b2    = (const float*)d_in[7];
  const float* ln1_g = (const float*)d_in[8];
  const float* ln1_b = (const float*)d_in[9];
  const float* ln2_g = (const float*)d_in[10];
  const float* ln2_b = (const float*)d_in[11];
  float* out = (float*)d_out;

  const size_t MC = (size_t)M_ * C_;
  float* ws  = (float*)d_ws;
  float* xo  = ws;
  float* h   = ws + MC;
  float* qkv = ws + 2 * MC;
  float* ff1 = qkv;

  ln_kernel<<<M_, 256, 0, stream>>>(x, ln1_g, ln1_b, h);
  qkv_kernel<<<dim3(DH / 64, M_ / 64, 3 * H_), 256, 0, stream>>>(h, wq, wk, wv, qkv);
  attn_kernel<<<dim3(T_ / BQ, B_ * H_), 256, 0, stream>>>(qkv, qkv + MC, qkv + 2 * MC,
                                                          x, xo);
  ln_kernel<<<M_, 256, 0, stream>>>(xo, ln2_g, ln2_b, h);
  ff1_kernel<<<dim3(DFF / 64, M_ / 64), 256, 0, stream>>>(h, w1, b1, ff1);
  ff2_kernel<<<dim3(C_ / 64, M_ / 64), 256, 0, stream>>>(ff1, w2, b2, xo, out);
}

// Round 3
// 752.064 us; speedup vs baseline: 6.4977x; 3.8365x over previous
//
#include <hip/hip_runtime.h>
#include <hip/hip_bf16.h>
#include <math.h>

#define B_   4
#define T_   2048
#define C_   1024
#define H_   8
#define DH   128
#define DFF  4096
#define M_   (B_*T_)   // 8192 rows

typedef __attribute__((ext_vector_type(8))) short bf16x8;
typedef __attribute__((ext_vector_type(4))) float f32x4;

__device__ __forceinline__ unsigned short f2bf(float x) {
  union { float f; unsigned u; } v; v.f = x;
  return (unsigned short)((v.u + 0x7fffu + ((v.u >> 16) & 1u)) >> 16);
}
__device__ __forceinline__ float bf2f(unsigned short h) {
  union { unsigned u; float f; } v; v.u = ((unsigned)h) << 16; return v.f;
}

__device__ __forceinline__ f32x4 mfma_bf16(bf16x8 a, bf16x8 b, f32x4 c) {
  return __builtin_amdgcn_mfma_f32_16x16x32_bf16(a, b, c, 0, 0, 0);
}

// async global->LDS, 16B per lane; HW places lane i at wave-base + i*16
__device__ __forceinline__ void gll16(const void* g, void* l) {
  __builtin_amdgcn_global_load_lds((const __attribute__((address_space(1))) void*)g,
                                   (__attribute__((address_space(3))) void*)l,
                                   16, 0, 0);
}

// ---------------------------------------------------------------------------
// LayerNorm: one block per row, 256 threads, 4 floats/thread.
// Emits hi/lo split bf16 (hi = RNE bf16 == the "plain bf16" value; lo = resid)
// ---------------------------------------------------------------------------
__global__ __launch_bounds__(256) void ln_kernel(const float* __restrict__ in,
                                                 const float* __restrict__ g,
                                                 const float* __restrict__ bb,
                                                 unsigned short* __restrict__ h_hi,
                                                 unsigned short* __restrict__ h_lo) {
  __shared__ float red[8];
  const int row = blockIdx.x;
  const int tid = threadIdx.x;
  const float* p = in + (size_t)row * C_;
  const float4 xv = *(const float4*)(p + (tid << 2));
  float s  = xv.x + xv.y + xv.z + xv.w;
  float sq = xv.x*xv.x + xv.y*xv.y + xv.z*xv.z + xv.w*xv.w;
  #pragma unroll
  for (int off = 32; off > 0; off >>= 1) {
    s  += __shfl_xor(s, off);
    sq += __shfl_xor(sq, off);
  }
  if ((tid & 63) == 0) { red[(tid >> 6) * 2] = s; red[(tid >> 6) * 2 + 1] = sq; }
  __syncthreads();
  s  = red[0] + red[2] + red[4] + red[6];
  sq = red[1] + red[3] + red[5] + red[7];
  const float mu  = s * (1.0f / C_);
  const float var = sq * (1.0f / C_) - mu * mu;
  const float rs  = rsqrtf(var + 1e-5f);
  const float4 gv = *(const float4*)(g  + (tid << 2));
  const float4 bv = *(const float4*)(bb + (tid << 2));
  float ov[4];
  ov[0] = (xv.x - mu) * rs * gv.x + bv.x;
  ov[1] = (xv.y - mu) * rs * gv.y + bv.y;
  ov[2] = (xv.z - mu) * rs * gv.z + bv.z;
  ov[3] = (xv.w - mu) * rs * gv.w + bv.w;
  ushort4 hv, lv;
  unsigned short* hp = (unsigned short*)&hv;
  unsigned short* lp = (unsigned short*)&lv;
  #pragma unroll
  for (int j = 0; j < 4; ++j) {
    hp[j] = f2bf(ov[j]);
    lp[j] = f2bf(ov[j] - bf2f(hp[j]));
  }
  *(ushort4*)(h_hi + (size_t)row * C_ + (tid << 2)) = hv;
  *(ushort4*)(h_lo + (size_t)row * C_ + (tid << 2)) = lv;
}

// ---------------------------------------------------------------------------
// Weight converters.
// cvt_t: out[c][r] = bf16(in[r][c])  (transpose to n-major k-contiguous)
// ---------------------------------------------------------------------------
__global__ __launch_bounds__(256) void cvt_t_kernel(const float* __restrict__ in,
                                                    unsigned short* __restrict__ out,
                                                    int R, int CC) {
  __shared__ float tile[32][33];
  const int r0 = blockIdx.y << 5, c0 = blockIdx.x << 5;
  const int tr = threadIdx.x >> 3, tc4 = (threadIdx.x & 7) << 2;
  const float4 vv = *(const float4*)(in + (size_t)(r0 + tr) * CC + c0 + tc4);
  tile[tr][tc4+0] = vv.x; tile[tr][tc4+1] = vv.y;
  tile[tr][tc4+2] = vv.z; tile[tr][tc4+3] = vv.w;
  __syncthreads();
  ushort4 o;
  o.x = f2bf(tile[tc4+0][tr]); o.y = f2bf(tile[tc4+1][tr]);
  o.z = f2bf(tile[tc4+2][tr]); o.w = f2bf(tile[tc4+3][tr]);
  *(ushort4*)(out + (size_t)(c0 + tr) * R + r0 + tc4) = o;
}

// split hi/lo transpose for wq/wk/wv: in [H][C][DH] -> out[z][DH][C], z=which*8+h
__global__ __launch_bounds__(256) void cvt_qkv_kernel(const float* __restrict__ wq,
                                                      const float* __restrict__ wk,
                                                      const float* __restrict__ wv,
                                                      unsigned short* __restrict__ wt_hi,
                                                      unsigned short* __restrict__ wt_lo) {
  const int z = blockIdx.z;
  const int which = z >> 3, head = z & 7;
  const float* in = (which == 0 ? wq : (which == 1 ? wk : wv)) + (size_t)head * C_ * DH;
  unsigned short* oh = wt_hi + (size_t)z * DH * C_;
  unsigned short* ol = wt_lo + (size_t)z * DH * C_;
  __shared__ float tile[32][33];
  const int r0 = blockIdx.y << 5, c0 = blockIdx.x << 5;   // r over C, c over DH
  const int tr = threadIdx.x >> 3, tc4 = (threadIdx.x & 7) << 2;
  const float4 vv = *(const float4*)(in + (size_t)(r0 + tr) * DH + c0 + tc4);
  tile[tr][tc4+0] = vv.x; tile[tr][tc4+1] = vv.y;
  tile[tr][tc4+2] = vv.z; tile[tr][tc4+3] = vv.w;
  __syncthreads();
  ushort4 hv, lv;
  unsigned short* hp = (unsigned short*)&hv;
  unsigned short* lp = (unsigned short*)&lv;
  #pragma unroll
  for (int j = 0; j < 4; ++j) {
    const float val = tile[tc4+j][tr];
    hp[j] = f2bf(val);
    lp[j] = f2bf(val - bf2f(hp[j]));
  }
  *(ushort4*)(oh + (size_t)(c0 + tr) * C_ + r0 + tc4) = hv;
  *(ushort4*)(ol + (size_t)(c0 + tr) * C_ + r0 + tc4) = lv;
}

// ---------------------------------------------------------------------------
// MFMA GEMM core: 128x128 tile, BK=32, 256 threads (4 waves, 2x2 wave grid),
// each wave 64x64 = 4x4 MFMA 16x16x32 tiles. A [M][K] k-contig, B [N][K]
// k-contig (both bf16). TERMS=3 adds split-precision: Ah*Bh + Ah*Bl + Al*Bh.
// LDS tiles row-major [128][32] (64B rows) -> lane order matches
// global_load_lds's base+lane*16 placement; b128 frag reads hit the 8-cycle
// floor (uniform 8 lanes/bank-group).
// ---------------------------------------------------------------------------
template<int TERMS>
__device__ __forceinline__ void gemm128_mfma(
    const unsigned short* __restrict__ Ah, const unsigned short* __restrict__ Al,
    int lda,
    const unsigned short* __restrict__ Bh, const unsigned short* __restrict__ Bl,
    int ldb, int K, f32x4 (&acc)[4][4],
    unsigned short* AhS, unsigned short* AlS,
    unsigned short* BhS, unsigned short* BlS) {
  const int tid  = threadIdx.x;
  const int w    = tid >> 6;
  const int lane = tid & 63;
  const int l15  = lane & 15, quad = lane >> 4;
  const int srow = lane >> 2, skc = (lane & 3) << 3;
  const int wm = w & 1, wn = w >> 1;

  for (int k0 = 0; k0 < K; k0 += 32) {
    __syncthreads();   // prior frag reads done before DMA overwrites LDS
    #pragma unroll
    for (int i = 0; i < 2; ++i) {
      const int seg  = w * 2 + i;              // 0..7
      const int r    = seg * 16 + srow;        // 0..127
      const int lofs = seg * 512 + lane * 8;   // shorts
      gll16(Ah + (size_t)r * lda + k0 + skc, AhS + lofs);
      gll16(Bh + (size_t)r * ldb + k0 + skc, BhS + lofs);
      if (TERMS == 3) {
        gll16(Al + (size_t)r * lda + k0 + skc, AlS + lofs);
        gll16(Bl + (size_t)r * ldb + k0 + skc, BlS + lofs);
      }
    }
    __syncthreads();   // drains vmcnt (compiler emits waitcnt before barrier)
    bf16x8 aH[4], bH[4], aL[4], bL[4];
    #pragma unroll
    for (int t = 0; t < 4; ++t) {
      aH[t] = *(const bf16x8*)&AhS[(wm * 64 + t * 16 + l15) * 32 + quad * 8];
      bH[t] = *(const bf16x8*)&BhS[(wn * 64 + t * 16 + l15) * 32 + quad * 8];
      if (TERMS == 3) {
        aL[t] = *(const bf16x8*)&AlS[(wm * 64 + t * 16 + l15) * 32 + quad * 8];
        bL[t] = *(const bf16x8*)&BlS[(wn * 64 + t * 16 + l15) * 32 + quad * 8];
      }
    }
    #pragma unroll
    for (int rt = 0; rt < 4; ++rt)
      #pragma unroll
      for (int ct = 0; ct < 4; ++ct) {
        if (TERMS == 3) {
          acc[rt][ct] = mfma_bf16(aL[rt], bH[ct], acc[rt][ct]);
          acc[rt][ct] = mfma_bf16(aH[rt], bL[ct], acc[rt][ct]);
        }
        acc[rt][ct] = mfma_bf16(aH[rt], bH[ct], acc[rt][ct]);
      }
  }
}

// ---------------------------------------------------------------------------
// QKV: split-precision MFMA GEMM. grid = (M/128=64, 3*H=24).
// q,k out [bh][t][d] fp32; v out transposed [bh][d][t] fp32 (float4 along t).
// ---------------------------------------------------------------------------
__global__ __launch_bounds__(256) void qkvm_kernel(const unsigned short* __restrict__ h_hi,
                                                   const unsigned short* __restrict__ h_lo,
                                                   const unsigned short* __restrict__ wt_hi,
                                                   const unsigned short* __restrict__ wt_lo,
                                                   float* __restrict__ q,
                                                   float* __restrict__ k,
                                                   float* __restrict__ v) {
  __shared__ __align__(16) unsigned short AhS[4096], AlS[4096];
  __shared__ __align__(16) unsigned short BhS[4096], BlS[4096];
  const int m0 = blockIdx.x << 7;
  const int z  = blockIdx.y;
  const int which = z >> 3, head = z & 7;
  f32x4 acc[4][4];
  #pragma unroll
  for (int i = 0; i < 4; ++i)
    #pragma unroll
    for (int j = 0; j < 4; ++j)
      #pragma unroll
      for (int r = 0; r < 4; ++r) acc[i][j][r] = 0.f;
  gemm128_mfma<3>(h_hi + (size_t)m0 * C_, h_lo + (size_t)m0 * C_, C_,
                  wt_hi + (size_t)z * DH * C_, wt_lo + (size_t)z * DH * C_, C_,
                  C_, acc, AhS, AlS, BhS, BlS);
  const int lane = threadIdx.x & 63, w = threadIdx.x >> 6;
  const int l15 = lane & 15, quad = lane >> 4;
  const int wm = w & 1, wn = w >> 1;
  const int b  = m0 >> 11;
  const int bh = b * H_ + head;
  if (which < 2) {
    float* outp = (which == 0 ? q : k);
    #pragma unroll
    for (int rt = 0; rt < 4; ++rt)
      #pragma unroll
      for (int ct = 0; ct < 4; ++ct) {
        const int d = wn * 64 + ct * 16 + l15;
        #pragma unroll
        for (int r = 0; r < 4; ++r) {
          const int t = (m0 & (T_ - 1)) + wm * 64 + rt * 16 + quad * 4 + r;
          outp[((size_t)bh * T_ + t) * DH + d] = acc[rt][ct][r];
        }
      }
  } else {
    #pragma unroll
    for (int rt = 0; rt < 4; ++rt)
      #pragma unroll
      for (int ct = 0; ct < 4; ++ct) {
        const int d  = wn * 64 + ct * 16 + l15;
        const int t0 = (m0 & (T_ - 1)) + wm * 64 + rt * 16 + quad * 4;
        *(float4*)&v[((size_t)bh * DH + d) * T_ + t0] =
            make_float4(acc[rt][ct][0], acc[rt][ct][1], acc[rt][ct][2], acc[rt][ct][3]);
      }
  }
}

// ---------------------------------------------------------------------------
// FF1: ff1 = bf16(relu(h2 @ w1 + b1)).  grid = (DFF/128=32, M/128=64)
// ---------------------------------------------------------------------------
__global__ __launch_bounds__(256) void ff1_kernel(const unsigned short* __restrict__ h2,
                                                  const unsigned short* __restrict__ w1t,
                                                  const float* __restrict__ b1,
                                                  unsigned short* __restrict__ ff1) {
  __shared__ __align__(16) unsigned short AhS[4096], BhS[4096];
  const int n0 = blockIdx.x << 7;
  const int m0 = blockIdx.y << 7;
  f32x4 acc[4][4];
  #pragma unroll
  for (int i = 0; i < 4; ++i)
    #pragma unroll
    for (int j = 0; j < 4; ++j)
      #pragma unroll
      for (int r = 0; r < 4; ++r) acc[i][j][r] = 0.f;
  gemm128_mfma<1>(h2 + (size_t)m0 * C_, nullptr, C_,
                  w1t + (size_t)n0 * C_, nullptr, C_,
                  C_, acc, AhS, nullptr, BhS, nullptr);
  const int lane = threadIdx.x & 63, w = threadIdx.x >> 6;
  const int l15 = lane & 15, quad = lane >> 4;
  const int wm = w & 1, wn = w >> 1;
  #pragma unroll
  for (int rt = 0; rt < 4; ++rt)
    #pragma unroll
    for (int ct = 0; ct < 4; ++ct) {
      const int n = n0 + wn * 64 + ct * 16 + l15;
      const float bias = b1[n];
      #pragma unroll
      for (int r = 0; r < 4; ++r) {
        const int m = m0 + wm * 64 + rt * 16 + quad * 4 + r;
        ff1[(size_t)m * DFF + n] = f2bf(fmaxf(acc[rt][ct][r] + bias, 0.f));
      }
    }
}

// ---------------------------------------------------------------------------
// FF2: out = ff1 @ w2 + b2 + xo.  grid = (C/128=8, M/128=64)
// ---------------------------------------------------------------------------
__global__ __launch_bounds__(256) void ff2_kernel(const unsigned short* __restrict__ ff1,
                                                  const unsigned short* __restrict__ w2t,
                                                  const float* __restrict__ b2,
                                                  const float* __restrict__ xo,
                                                  float* __restrict__ out) {
  __shared__ __align__(16) unsigned short AhS[4096], BhS[4096];
  const int n0 = blockIdx.x << 7;
  const int m0 = blockIdx.y << 7;
  f32x4 acc[4][4];
  #pragma unroll
  for (int i = 0; i < 4; ++i)
    #pragma unroll
    for (int j = 0; j < 4; ++j)
      #pragma unroll
      for (int r = 0; r < 4; ++r) acc[i][j][r] = 0.f;
  gemm128_mfma<1>(ff1 + (size_t)m0 * DFF, nullptr, DFF,
                  w2t + (size_t)n0 * DFF, nullptr, DFF,
                  DFF, acc, AhS, nullptr, BhS, nullptr);
  const int lane = threadIdx.x & 63, w = threadIdx.x >> 6;
  const int l15 = lane & 15, quad = lane >> 4;
  const int wm = w & 1, wn = w >> 1;
  #pragma unroll
  for (int rt = 0; rt < 4; ++rt)
    #pragma unroll
    for (int ct = 0; ct < 4; ++ct) {
      const int n = n0 + wn * 64 + ct * 16 + l15;
      const float bias = b2[n];
      #pragma unroll
      for (int r = 0; r < 4; ++r) {
        const int m = m0 + wm * 64 + rt * 16 + quad * 4 + r;
        out[(size_t)m * C_ + n] = acc[rt][ct][r] + bias + xo[(size_t)m * C_ + n];
      }
    }
}

// ---------------------------------------------------------------------------
// MFMA flash attention (unchanged from R1 — verified).
// ---------------------------------------------------------------------------
#define BQ   128
#define BK   32
#define KSTR 136
#define VSTR 40

__global__ __launch_bounds__(256, 2) void attn_kernel(const float* __restrict__ q,
                                                      const float* __restrict__ k,
                                                      const float* __restrict__ vt,
                                                      const float* __restrict__ x,
                                                      float* __restrict__ xo) {
  __shared__ __align__(16) unsigned short KhS[BK * KSTR];
  __shared__ __align__(16) unsigned short KlS[BK * KSTR];
  __shared__ __align__(16) unsigned short VtS[DH * VSTR];
  __shared__ __align__(16) unsigned short PS [BQ * VSTR];

  const int bh  = blockIdx.y;
  const int qt0 = blockIdx.x * BQ;
  const int tid  = threadIdx.x;
  const int w    = tid >> 6;
  const int lane = tid & 63;
  const int l15  = lane & 15;
  const int quad = lane >> 4;

  const float* qb = q  + (size_t)bh * T_ * DH;
  const float* kb = k  + (size_t)bh * T_ * DH;
  const float* vb = vt + (size_t)bh * DH * T_;

  bf16x8 Qh[2][4], Ql[2][4];
  #pragma unroll
  for (int rt = 0; rt < 2; ++rt) {
    const int row = qt0 + w * 32 + rt * 16 + l15;
    #pragma unroll
    for (int kc = 0; kc < 4; ++kc) {
      const float* p = qb + (size_t)row * DH + kc * 32 + quad * 8;
      const float4 a = *(const float4*)p;
      const float4 b = *(const float4*)(p + 4);
      const float xs[8] = {a.x, a.y, a.z, a.w, b.x, b.y, b.z, b.w};
      bf16x8 hv, lv;
      #pragma unroll
      for (int j = 0; j < 8; ++j) {
        const unsigned short hb = f2bf(xs[j]);
        hv[j] = (short)hb;
        lv[j] = (short)f2bf(xs[j] - bf2f(hb));
      }
      Qh[rt][kc] = hv; Ql[rt][kc] = lv;
    }
  }

  f32x4 O[2][8];
  #pragma unroll
  for (int rt = 0; rt < 2; ++rt)
    #pragma unroll
    for (int n = 0; n < 8; ++n)
      #pragma unroll
      for (int r = 0; r < 4; ++r) O[rt][n][r] = 0.f;
  float m_i[2][4], l_i[2][4];
  #pragma unroll
  for (int rt = 0; rt < 2; ++rt)
    #pragma unroll
    for (int r = 0; r < 4; ++r) { m_i[rt][r] = -1e30f; l_i[rt][r] = 0.f; }

  const float sc = 11.313708498984761f;

  for (int kt = 0; kt < T_; kt += BK) {
    __syncthreads();
    #pragma unroll
    for (int i = 0; i < 4; ++i) {
      const int f = i * 256 + tid;
      const int key = f >> 5, d4 = (f & 31) << 2;
      const float4 kv = *(const float4*)(kb + (size_t)(kt + key) * DH + d4);
      const float xs[4] = {kv.x, kv.y, kv.z, kv.w};
      unsigned short hh[4], ll[4];
      #pragma unroll
      for (int j = 0; j < 4; ++j) {
        hh[j] = f2bf(xs[j]);
        ll[j] = f2bf(xs[j] - bf2f(hh[j]));
      }
      uint2 hp, lp;
      hp.x = (unsigned)hh[0] | ((unsigned)hh[1] << 16);
      hp.y = (unsigned)hh[2] | ((unsigned)hh[3] << 16);
      lp.x = (unsigned)ll[0] | ((unsigned)ll[1] << 16);
      lp.y = (unsigned)ll[2] | ((unsigned)ll[3] << 16);
      *(uint2*)&KhS[key * KSTR + d4] = hp;
      *(uint2*)&KlS[key * KSTR + d4] = lp;
    }
    #pragma unroll
    for (int i = 0; i < 4; ++i) {
      const int f = i * 256 + tid;
      const int d = f >> 3, k4 = (f & 7) << 2;
      const float4 vv = *(const float4*)(vb + (size_t)d * T_ + kt + k4);
      uint2 vp;
      vp.x = (unsigned)f2bf(vv.x) | ((unsigned)f2bf(vv.y) << 16);
      vp.y = (unsigned)f2bf(vv.z) | ((unsigned)f2bf(vv.w) << 16);
      *(uint2*)&VtS[d * VSTR + k4] = vp;
    }
    __syncthreads();

    f32x4 S[2][2];
    #pragma unroll
    for (int rt = 0; rt < 2; ++rt)
      #pragma unroll
      for (int ct = 0; ct < 2; ++ct)
        #pragma unroll
        for (int r = 0; r < 4; ++r) S[rt][ct][r] = 0.f;
    #pragma unroll
    for (int kc = 0; kc < 4; ++kc) {
      const int off = kc * 32 + quad * 8;
      const bf16x8 bh0 = *(const bf16x8*)&KhS[(l15)      * KSTR + off];
      const bf16x8 bh1 = *(const bf16x8*)&KhS[(16 + l15) * KSTR + off];
      const bf16x8 bl0 = *(const bf16x8*)&KlS[(l15)      * KSTR + off];
      const bf16x8 bl1 = *(const bf16x8*)&KlS[(16 + l15) * KSTR + off];
      #pragma unroll
      for (int rt = 0; rt < 2; ++rt) {
        S[rt][0] = mfma_bf16(Ql[rt][kc], bh0, S[rt][0]);
        S[rt][0] = mfma_bf16(Qh[rt][kc], bl0, S[rt][0]);
        S[rt][0] = mfma_bf16(Qh[rt][kc], bh0, S[rt][0]);
        S[rt][1] = mfma_bf16(Ql[rt][kc], bh1, S[rt][1]);
        S[rt][1] = mfma_bf16(Qh[rt][kc], bl1, S[rt][1]);
        S[rt][1] = mfma_bf16(Qh[rt][kc], bh1, S[rt][1]);
      }
    }

    #pragma unroll
    for (int rt = 0; rt < 2; ++rt) {
      #pragma unroll
      for (int r = 0; r < 4; ++r) {
        const float s0 = S[rt][0][r] * sc;
        const float s1 = S[rt][1][r] * sc;
        float mx = fmaxf(s0, s1);
        #pragma unroll
        for (int msk = 1; msk < 16; msk <<= 1) mx = fmaxf(mx, __shfl_xor(mx, msk));
        const float m_new = fmaxf(m_i[rt][r], mx);
        const float alpha = __expf(m_i[rt][r] - m_new);
        m_i[rt][r] = m_new;
        const float p0 = __expf(s0 - m_new);
        const float p1 = __expf(s1 - m_new);
        float rs = p0 + p1;
        #pragma unroll
        for (int msk = 1; msk < 16; msk <<= 1) rs += __shfl_xor(rs, msk);
        l_i[rt][r] = l_i[rt][r] * alpha + rs;
        #pragma unroll
        for (int n = 0; n < 8; ++n) O[rt][n][r] *= alpha;
        const int prow = w * 32 + rt * 16 + quad * 4 + r;
        PS[prow * VSTR + l15]      = f2bf(p0);
        PS[prow * VSTR + 16 + l15] = f2bf(p1);
      }
    }
    __syncthreads();

    bf16x8 aP[2];
    #pragma unroll
    for (int rt = 0; rt < 2; ++rt)
      aP[rt] = *(const bf16x8*)&PS[(w * 32 + rt * 16 + l15) * VSTR + quad * 8];
    #pragma unroll
    for (int n = 0; n < 8; ++n) {
      const bf16x8 bv = *(const bf16x8*)&VtS[(n * 16 + l15) * VSTR + quad * 8];
      O[0][n] = mfma_bf16(aP[0], bv, O[0][n]);
      O[1][n] = mfma_bf16(aP[1], bv, O[1][n]);
    }
  }

  const int b = bh >> 3, hh = bh & 7;
  #pragma unroll
  for (int rt = 0; rt < 2; ++rt) {
    #pragma unroll
    for (int r = 0; r < 4; ++r) {
      const float inv_l = 1.0f / l_i[rt][r];
      const int t = qt0 + w * 32 + rt * 16 + quad * 4 + r;
      const size_t xrow = ((size_t)(b * T_ + t)) * C_ + (size_t)hh * DH;
      #pragma unroll
      for (int n = 0; n < 8; ++n) {
        const int d = n * 16 + l15;
        xo[xrow + d] = x[xrow + d] + O[rt][n][r] * inv_l;
      }
    }
  }
}

// ---------------------------------------------------------------------------
// Workspace layout (byte offsets):
//   0   MB: xo     f32  [M][C]            32 MB
//   32  MB: q      f32  [bh][t][d]        32 MB   \
//   64  MB: k      f32  [bh][t][d]        32 MB    } ff1 bf16 [M][DFF] (64MB)
//   96  MB: v      f32  [bh][d][t]        32 MB   /  aliases q..v after attn
//   128 MB: h_hi   bf16 [M][C]            16 MB
//   144 MB: h_lo   bf16 [M][C]            16 MB
//   160 MB: w1t    bf16 [DFF][C]           8 MB
//   168 MB: w2t    bf16 [C][DFF]           8 MB
//   176 MB: wt_hi  bf16 [3*H][DH][C]       6 MB
//   182 MB: wt_lo  bf16 [3*H][DH][C]       6 MB
// total 188 MB
// ---------------------------------------------------------------------------
extern "C" void kernel_launch(void* const* d_in, const int* in_sizes, int n_in,
                              void* d_out, int out_size, void* d_ws, size_t ws_size,
                              hipStream_t stream) {
  (void)in_sizes; (void)n_in; (void)out_size; (void)ws_size;
  const float* x     = (const float*)d_in[0];
  const float* wq    = (const float*)d_in[1];
  const float* wk    = (const float*)d_in[2];
  const float* wv    = (const float*)d_in[3];
  const float* w1    = (const float*)d_in[4];
  const float* b1    = (const float*)d_in[5];
  const float* w2    = (const float*)d_in[6];
  const float* b2    = (const float*)d_in[7];
  const float* ln1_g = (const float*)d_in[8];
  const float* ln1_b = (const float*)d_in[9];
  const float* ln2_g = (const float*)d_in[10];
  const float* ln2_b = (const float*)d_in[11];
  float* out = (float*)d_out;

  char* W = (char*)d_ws;
  float* xo = (float*)(W);
  float* q  = (float*)(W + (32u << 20));
  float* k  = (float*)(W + (64u << 20));
  float* v  = (float*)(W + (96u << 20));
  unsigned short* ff1   = (unsigned short*)(W + (32u << 20));
  unsigned short* h_hi  = (unsigned short*)(W + (128u << 20));
  unsigned short* h_lo  = (unsigned short*)(W + (144u << 20));
  unsigned short* w1t   = (unsigned short*)(W + (160u << 20));
  unsigned short* w2t   = (unsigned short*)(W + (168u << 20));
  unsigned short* wt_hi = (unsigned short*)(W + (176u << 20));
  unsigned short* wt_lo = (unsigned short*)(W + (182u << 20));

  cvt_t_kernel<<<dim3(DFF / 32, C_ / 32), 256, 0, stream>>>(w1, w1t, C_, DFF);
  cvt_t_kernel<<<dim3(C_ / 32, DFF / 32), 256, 0, stream>>>(w2, w2t, DFF, C_);
  cvt_qkv_kernel<<<dim3(DH / 32, C_ / 32, 24), 256, 0, stream>>>(wq, wk, wv, wt_hi, wt_lo);
  ln_kernel<<<M_, 256, 0, stream>>>(x, ln1_g, ln1_b, h_hi, h_lo);
  qkvm_kernel<<<dim3(M_ / 128, 24), 256, 0, stream>>>(h_hi, h_lo, wt_hi, wt_lo, q, k, v);
  attn_kernel<<<dim3(T_ / BQ, B_ * H_), 256, 0, stream>>>(q, k, v, x, xo);
  ln_kernel<<<M_, 256, 0, stream>>>(xo, ln2_g, ln2_b, h_hi, h_lo);
  ff1_kernel<<<dim3(DFF / 128, M_ / 128), 256, 0, stream>>>(h_hi, w1t, b1, ff1);
  ff2_kernel<<<dim3(C_ / 128, M_ / 128), 256, 0, stream>>>(ff1, w2t, b2, xo, out);
}

// Round 4
// 714.688 us; speedup vs baseline: 6.8375x; 1.0523x over previous
//
#include <hip/hip_runtime.h>
#include <hip/hip_bf16.h>
#include <math.h>

#define B_   4
#define T_   2048
#define C_   1024
#define H_   8
#define DH   128
#define DFF  4096
#define M_   (B_*T_)   // 8192 rows

typedef __attribute__((ext_vector_type(8))) short bf16x8;
typedef __attribute__((ext_vector_type(4))) float f32x4;

// sqrt(128) * log2(e): scores computed directly in exp2 domain
#define SC2 16.32223094f

__device__ __forceinline__ unsigned short f2bf(float x) {
  union { float f; unsigned u; } v; v.f = x;
  return (unsigned short)((v.u + 0x7fffu + ((v.u >> 16) & 1u)) >> 16);
}
__device__ __forceinline__ float bf2f(unsigned short h) {
  union { unsigned u; float f; } v; v.u = ((unsigned)h) << 16; return v.f;
}

__device__ __forceinline__ f32x4 mfma_bf16(bf16x8 a, bf16x8 b, f32x4 c) {
  return __builtin_amdgcn_mfma_f32_16x16x32_bf16(a, b, c, 0, 0, 0);
}

// async global->LDS, 16B per lane; HW places lane i at wave-base + i*16
__device__ __forceinline__ void gll16(const void* g, void* l) {
  __builtin_amdgcn_global_load_lds((const __attribute__((address_space(1))) void*)g,
                                   (__attribute__((address_space(3))) void*)l,
                                   16, 0, 0);
}

// ---------------------------------------------------------------------------
// LayerNorm: one block per row, 256 threads; emits hi/lo split bf16.
// ---------------------------------------------------------------------------
__global__ __launch_bounds__(256) void ln_kernel(const float* __restrict__ in,
                                                 const float* __restrict__ g,
                                                 const float* __restrict__ bb,
                                                 unsigned short* __restrict__ h_hi,
                                                 unsigned short* __restrict__ h_lo) {
  __shared__ float red[8];
  const int row = blockIdx.x;
  const int tid = threadIdx.x;
  const float* p = in + (size_t)row * C_;
  const float4 xv = *(const float4*)(p + (tid << 2));
  float s  = xv.x + xv.y + xv.z + xv.w;
  float sq = xv.x*xv.x + xv.y*xv.y + xv.z*xv.z + xv.w*xv.w;
  #pragma unroll
  for (int off = 32; off > 0; off >>= 1) {
    s  += __shfl_xor(s, off);
    sq += __shfl_xor(sq, off);
  }
  if ((tid & 63) == 0) { red[(tid >> 6) * 2] = s; red[(tid >> 6) * 2 + 1] = sq; }
  __syncthreads();
  s  = red[0] + red[2] + red[4] + red[6];
  sq = red[1] + red[3] + red[5] + red[7];
  const float mu  = s * (1.0f / C_);
  const float var = sq * (1.0f / C_) - mu * mu;
  const float rs  = rsqrtf(var + 1e-5f);
  const float4 gv = *(const float4*)(g  + (tid << 2));
  const float4 bv = *(const float4*)(bb + (tid << 2));
  float ov[4];
  ov[0] = (xv.x - mu) * rs * gv.x + bv.x;
  ov[1] = (xv.y - mu) * rs * gv.y + bv.y;
  ov[2] = (xv.z - mu) * rs * gv.z + bv.z;
  ov[3] = (xv.w - mu) * rs * gv.w + bv.w;
  ushort4 hv, lv;
  unsigned short* hp = (unsigned short*)&hv;
  unsigned short* lp = (unsigned short*)&lv;
  #pragma unroll
  for (int j = 0; j < 4; ++j) {
    hp[j] = f2bf(ov[j]);
    lp[j] = f2bf(ov[j] - bf2f(hp[j]));
  }
  *(ushort4*)(h_hi + (size_t)row * C_ + (tid << 2)) = hv;
  *(ushort4*)(h_lo + (size_t)row * C_ + (tid << 2)) = lv;
}

// ---------------------------------------------------------------------------
// Weight converters (transpose to n-major k-contiguous bf16).
// ---------------------------------------------------------------------------
__global__ __launch_bounds__(256) void cvt_t_kernel(const float* __restrict__ in,
                                                    unsigned short* __restrict__ out,
                                                    int R, int CC) {
  __shared__ float tile[32][33];
  const int r0 = blockIdx.y << 5, c0 = blockIdx.x << 5;
  const int tr = threadIdx.x >> 3, tc4 = (threadIdx.x & 7) << 2;
  const float4 vv = *(const float4*)(in + (size_t)(r0 + tr) * CC + c0 + tc4);
  tile[tr][tc4+0] = vv.x; tile[tr][tc4+1] = vv.y;
  tile[tr][tc4+2] = vv.z; tile[tr][tc4+3] = vv.w;
  __syncthreads();
  ushort4 o;
  o.x = f2bf(tile[tc4+0][tr]); o.y = f2bf(tile[tc4+1][tr]);
  o.z = f2bf(tile[tc4+2][tr]); o.w = f2bf(tile[tc4+3][tr]);
  *(ushort4*)(out + (size_t)(c0 + tr) * R + r0 + tc4) = o;
}

// split hi/lo transpose for wq/wk/wv: in [H][C][DH] -> out[z][DH][C], z=which*8+h
__global__ __launch_bounds__(256) void cvt_qkv_kernel(const float* __restrict__ wq,
                                                      const float* __restrict__ wk,
                                                      const float* __restrict__ wv,
                                                      unsigned short* __restrict__ wt_hi,
                                                      unsigned short* __restrict__ wt_lo) {
  const int z = blockIdx.z;
  const int which = z >> 3, head = z & 7;
  const float* in = (which == 0 ? wq : (which == 1 ? wk : wv)) + (size_t)head * C_ * DH;
  unsigned short* oh = wt_hi + (size_t)z * DH * C_;
  unsigned short* ol = wt_lo + (size_t)z * DH * C_;
  __shared__ float tile[32][33];
  const int r0 = blockIdx.y << 5, c0 = blockIdx.x << 5;   // r over C, c over DH
  const int tr = threadIdx.x >> 3, tc4 = (threadIdx.x & 7) << 2;
  const float4 vv = *(const float4*)(in + (size_t)(r0 + tr) * DH + c0 + tc4);
  tile[tr][tc4+0] = vv.x; tile[tr][tc4+1] = vv.y;
  tile[tr][tc4+2] = vv.z; tile[tr][tc4+3] = vv.w;
  __syncthreads();
  ushort4 hv, lv;
  unsigned short* hp = (unsigned short*)&hv;
  unsigned short* lp = (unsigned short*)&lv;
  #pragma unroll
  for (int j = 0; j < 4; ++j) {
    const float val = tile[tc4+j][tr];
    hp[j] = f2bf(val);
    lp[j] = f2bf(val - bf2f(hp[j]));
  }
  *(ushort4*)(oh + (size_t)(c0 + tr) * C_ + r0 + tc4) = hv;
  *(ushort4*)(ol + (size_t)(c0 + tr) * C_ + r0 + tc4) = lv;
}

// ---------------------------------------------------------------------------
// MFMA GEMM core: 128x128 tile, BK=32, 256 threads (4 waves, 2x2 wave grid).
// A [M][K] k-contig bf16, B [N][K] k-contig bf16.
// TERMS=3: Ah*Bh + Ah*Bl + Al*Bh split-precision.
// ---------------------------------------------------------------------------
template<int TERMS>
__device__ __forceinline__ void gemm128_mfma(
    const unsigned short* __restrict__ Ah, const unsigned short* __restrict__ Al,
    int lda,
    const unsigned short* __restrict__ Bh, const unsigned short* __restrict__ Bl,
    int ldb, int K, f32x4 (&acc)[4][4],
    unsigned short* AhS, unsigned short* AlS,
    unsigned short* BhS, unsigned short* BlS) {
  const int tid  = threadIdx.x;
  const int w    = tid >> 6;
  const int lane = tid & 63;
  const int l15  = lane & 15, quad = lane >> 4;
  const int srow = lane >> 2, skc = (lane & 3) << 3;
  const int wm = w & 1, wn = w >> 1;

  for (int k0 = 0; k0 < K; k0 += 32) {
    __syncthreads();
    #pragma unroll
    for (int i = 0; i < 2; ++i) {
      const int seg  = w * 2 + i;
      const int r    = seg * 16 + srow;
      const int lofs = seg * 512 + lane * 8;
      gll16(Ah + (size_t)r * lda + k0 + skc, AhS + lofs);
      gll16(Bh + (size_t)r * ldb + k0 + skc, BhS + lofs);
      if (TERMS == 3) {
        gll16(Al + (size_t)r * lda + k0 + skc, AlS + lofs);
        gll16(Bl + (size_t)r * ldb + k0 + skc, BlS + lofs);
      }
    }
    __syncthreads();
    bf16x8 aH[4], bH[4], aL[4], bL[4];
    #pragma unroll
    for (int t = 0; t < 4; ++t) {
      aH[t] = *(const bf16x8*)&AhS[(wm * 64 + t * 16 + l15) * 32 + quad * 8];
      bH[t] = *(const bf16x8*)&BhS[(wn * 64 + t * 16 + l15) * 32 + quad * 8];
      if (TERMS == 3) {
        aL[t] = *(const bf16x8*)&AlS[(wm * 64 + t * 16 + l15) * 32 + quad * 8];
        bL[t] = *(const bf16x8*)&BlS[(wn * 64 + t * 16 + l15) * 32 + quad * 8];
      }
    }
    #pragma unroll
    for (int rt = 0; rt < 4; ++rt)
      #pragma unroll
      for (int ct = 0; ct < 4; ++ct) {
        if (TERMS == 3) {
          acc[rt][ct] = mfma_bf16(aL[rt], bH[ct], acc[rt][ct]);
          acc[rt][ct] = mfma_bf16(aH[rt], bL[ct], acc[rt][ct]);
        }
        acc[rt][ct] = mfma_bf16(aH[rt], bH[ct], acc[rt][ct]);
      }
  }
}

// ---------------------------------------------------------------------------
// QK projection (split precision). grid = (M/128=64, 2*H=16).
// which==0: q out [bh][t][d] bf16 hi/lo, PRE-SCALED by SC2 (exp2-domain).
// which==1: k out tile-image [bh][64 kt][4 kc][32 key][32 d] bf16 hi/lo.
// ---------------------------------------------------------------------------
__global__ __launch_bounds__(256) void qkm_kernel(const unsigned short* __restrict__ h_hi,
                                                  const unsigned short* __restrict__ h_lo,
                                                  const unsigned short* __restrict__ wt_hi,
                                                  const unsigned short* __restrict__ wt_lo,
                                                  unsigned short* __restrict__ q_hi,
                                                  unsigned short* __restrict__ q_lo,
                                                  unsigned short* __restrict__ k_hi,
                                                  unsigned short* __restrict__ k_lo) {
  __shared__ __align__(16) unsigned short AhS[4096], AlS[4096];
  __shared__ __align__(16) unsigned short BhS[4096], BlS[4096];
  const int m0 = blockIdx.x << 7;
  const int z  = blockIdx.y;
  const int which = z >> 3, head = z & 7;
  f32x4 acc[4][4];
  #pragma unroll
  for (int i = 0; i < 4; ++i)
    #pragma unroll
    for (int j = 0; j < 4; ++j)
      #pragma unroll
      for (int r = 0; r < 4; ++r) acc[i][j][r] = 0.f;
  gemm128_mfma<3>(h_hi + (size_t)m0 * C_, h_lo + (size_t)m0 * C_, C_,
                  wt_hi + (size_t)z * DH * C_, wt_lo + (size_t)z * DH * C_, C_,
                  C_, acc, AhS, AlS, BhS, BlS);
  const int lane = threadIdx.x & 63, w = threadIdx.x >> 6;
  const int l15 = lane & 15, quad = lane >> 4;
  const int wm = w & 1, wn = w >> 1;
  const int bh = (m0 >> 11) * H_ + head;
  const int tbase = (m0 & (T_ - 1)) + wm * 64 + quad * 4;
  if (which == 0) {
    #pragma unroll
    for (int rt = 0; rt < 4; ++rt)
      #pragma unroll
      for (int ct = 0; ct < 4; ++ct) {
        const int d = wn * 64 + ct * 16 + l15;
        #pragma unroll
        for (int r = 0; r < 4; ++r) {
          const int t = tbase + rt * 16 + r;
          const float val = acc[rt][ct][r] * SC2;
          const unsigned short hb = f2bf(val);
          const size_t idx = ((size_t)bh * T_ + t) * DH + d;
          q_hi[idx] = hb;
          q_lo[idx] = f2bf(val - bf2f(hb));
        }
      }
  } else {
    #pragma unroll
    for (int rt = 0; rt < 4; ++rt)
      #pragma unroll
      for (int ct = 0; ct < 4; ++ct) {
        const int d = wn * 64 + ct * 16 + l15;
        #pragma unroll
        for (int r = 0; r < 4; ++r) {
          const int t = tbase + rt * 16 + r;
          const float val = acc[rt][ct][r];
          const unsigned short hb = f2bf(val);
          const size_t idx = (((size_t)bh * 64 + (t >> 5)) * 4 + (d >> 5)) * 1024
                           + (size_t)(t & 31) * 32 + (d & 31);
          k_hi[idx] = hb;
          k_lo[idx] = f2bf(val - bf2f(hb));
        }
      }
  }
}

// ---------------------------------------------------------------------------
// V projection (plain bf16). grid = (M/128=64, H=8).
// v out tile-image [bh][64 kt][128 d][32 key] bf16.
// ---------------------------------------------------------------------------
__global__ __launch_bounds__(256) void vm_kernel(const unsigned short* __restrict__ h_hi,
                                                 const unsigned short* __restrict__ wv_hi,
                                                 unsigned short* __restrict__ vimg) {
  __shared__ __align__(16) unsigned short AhS[4096], BhS[4096];
  const int m0 = blockIdx.x << 7;
  const int head = blockIdx.y;
  f32x4 acc[4][4];
  #pragma unroll
  for (int i = 0; i < 4; ++i)
    #pragma unroll
    for (int j = 0; j < 4; ++j)
      #pragma unroll
      for (int r = 0; r < 4; ++r) acc[i][j][r] = 0.f;
  gemm128_mfma<1>(h_hi + (size_t)m0 * C_, nullptr, C_,
                  wv_hi + (size_t)(16 + head) * DH * C_, nullptr, C_,
                  C_, acc, AhS, nullptr, BhS, nullptr);
  const int lane = threadIdx.x & 63, w = threadIdx.x >> 6;
  const int l15 = lane & 15, quad = lane >> 4;
  const int wm = w & 1, wn = w >> 1;
  const int bh = (m0 >> 11) * H_ + head;
  #pragma unroll
  for (int rt = 0; rt < 4; ++rt)
    #pragma unroll
    for (int ct = 0; ct < 4; ++ct) {
      const int d  = wn * 64 + ct * 16 + l15;
      const int t0 = (m0 & (T_ - 1)) + wm * 64 + rt * 16 + quad * 4;
      ushort4 pk;
      pk.x = f2bf(acc[rt][ct][0]); pk.y = f2bf(acc[rt][ct][1]);
      pk.z = f2bf(acc[rt][ct][2]); pk.w = f2bf(acc[rt][ct][3]);
      *(ushort4*)&vimg[(((size_t)bh * 64 + (t0 >> 5)) * 128 + d) * 32 + (t0 & 31)] = pk;
    }
}

// ---------------------------------------------------------------------------
// FF1: ff1 = bf16(relu(h2 @ w1 + b1)).  grid = (DFF/128=32, M/128=64)
// ---------------------------------------------------------------------------
__global__ __launch_bounds__(256) void ff1_kernel(const unsigned short* __restrict__ h2,
                                                  const unsigned short* __restrict__ w1t,
                                                  const float* __restrict__ b1,
                                                  unsigned short* __restrict__ ff1) {
  __shared__ __align__(16) unsigned short AhS[4096], BhS[4096];
  const int n0 = blockIdx.x << 7;
  const int m0 = blockIdx.y << 7;
  f32x4 acc[4][4];
  #pragma unroll
  for (int i = 0; i < 4; ++i)
    #pragma unroll
    for (int j = 0; j < 4; ++j)
      #pragma unroll
      for (int r = 0; r < 4; ++r) acc[i][j][r] = 0.f;
  gemm128_mfma<1>(h2 + (size_t)m0 * C_, nullptr, C_,
                  w1t + (size_t)n0 * C_, nullptr, C_,
                  C_, acc, AhS, nullptr, BhS, nullptr);
  const int lane = threadIdx.x & 63, w = threadIdx.x >> 6;
  const int l15 = lane & 15, quad = lane >> 4;
  const int wm = w & 1, wn = w >> 1;
  #pragma unroll
  for (int rt = 0; rt < 4; ++rt)
    #pragma unroll
    for (int ct = 0; ct < 4; ++ct) {
      const int n = n0 + wn * 64 + ct * 16 + l15;
      const float bias = b1[n];
      #pragma unroll
      for (int r = 0; r < 4; ++r) {
        const int m = m0 + wm * 64 + rt * 16 + quad * 4 + r;
        ff1[(size_t)m * DFF + n] = f2bf(fmaxf(acc[rt][ct][r] + bias, 0.f));
      }
    }
}

// ---------------------------------------------------------------------------
// FF2: out = ff1 @ w2 + b2 + xo.  grid = (C/128=8, M/128=64)
// ---------------------------------------------------------------------------
__global__ __launch_bounds__(256) void ff2_kernel(const unsigned short* __restrict__ ff1,
                                                  const unsigned short* __restrict__ w2t,
                                                  const float* __restrict__ b2,
                                                  const float* __restrict__ xo,
                                                  float* __restrict__ out) {
  __shared__ __align__(16) unsigned short AhS[4096], BhS[4096];
  const int n0 = blockIdx.x << 7;
  const int m0 = blockIdx.y << 7;
  f32x4 acc[4][4];
  #pragma unroll
  for (int i = 0; i < 4; ++i)
    #pragma unroll
    for (int j = 0; j < 4; ++j)
      #pragma unroll
      for (int r = 0; r < 4; ++r) acc[i][j][r] = 0.f;
  gemm128_mfma<1>(ff1 + (size_t)m0 * DFF, nullptr, DFF,
                  w2t + (size_t)n0 * DFF, nullptr, DFF,
                  DFF, acc, AhS, nullptr, BhS, nullptr);
  const int lane = threadIdx.x & 63, w = threadIdx.x >> 6;
  const int l15 = lane & 15, quad = lane >> 4;
  const int wm = w & 1, wn = w >> 1;
  #pragma unroll
  for (int rt = 0; rt < 4; ++rt)
    #pragma unroll
    for (int ct = 0; ct < 4; ++ct) {
      const int n = n0 + wn * 64 + ct * 16 + l15;
      const float bias = b2[n];
      #pragma unroll
      for (int r = 0; r < 4; ++r) {
        const int m = m0 + wm * 64 + rt * 16 + quad * 4 + r;
        out[(size_t)m * C_ + n] = acc[rt][ct][r] + bias + xo[(size_t)m * C_ + n];
      }
    }
}

// ---------------------------------------------------------------------------
// MFMA flash attention, all-bf16 inputs pre-split/pre-scaled, DMA staging.
// BQ=128 (4 waves x 32 q-rows), BK=32. Softmax in exp2 domain.
// grid = (T/128=16, B*H=32), 256 threads.
// ---------------------------------------------------------------------------
#define BQ 128

__global__ __launch_bounds__(256, 2) void attn_kernel(
    const unsigned short* __restrict__ q_hi, const unsigned short* __restrict__ q_lo,
    const unsigned short* __restrict__ k_hi, const unsigned short* __restrict__ k_lo,
    const unsigned short* __restrict__ vimg,
    const float* __restrict__ x, float* __restrict__ xo) {
  __shared__ __align__(16) unsigned short KhS[4096];
  __shared__ __align__(16) unsigned short KlS[4096];
  __shared__ __align__(16) unsigned short VtS[4096];
  __shared__ __align__(16) unsigned short PS [4096];

  const int bh  = blockIdx.y;
  const int qt0 = blockIdx.x * BQ;
  const int tid  = threadIdx.x;
  const int w    = tid >> 6;
  const int lane = tid & 63;
  const int l15  = lane & 15;
  const int quad = lane >> 4;

  // ---- Q fragments (pre-scaled hi/lo bf16), direct global loads ----
  bf16x8 Qh[2][4], Ql[2][4];
  #pragma unroll
  for (int rt = 0; rt < 2; ++rt) {
    const int row = qt0 + w * 32 + rt * 16 + l15;
    #pragma unroll
    for (int kc = 0; kc < 4; ++kc) {
      const size_t off = ((size_t)bh * T_ + row) * DH + kc * 32 + quad * 8;
      Qh[rt][kc] = *(const bf16x8*)(q_hi + off);
      Ql[rt][kc] = *(const bf16x8*)(q_lo + off);
    }
  }

  f32x4 O[2][8];
  #pragma unroll
  for (int rt = 0; rt < 2; ++rt)
    #pragma unroll
    for (int n = 0; n < 8; ++n)
      #pragma unroll
      for (int r = 0; r < 4; ++r) O[rt][n][r] = 0.f;
  float m_i[2][4], l_i[2][4];
  #pragma unroll
  for (int rt = 0; rt < 2; ++rt)
    #pragma unroll
    for (int r = 0; r < 4; ++r) { m_i[rt][r] = -1e30f; l_i[rt][r] = 0.f; }

  for (int kt = 0; kt < T_ / 32; ++kt) {
    const size_t tb = ((size_t)bh * 64 + kt) * 4096;
    __syncthreads();   // prior tile's LDS reads complete
    #pragma unroll
    for (int i = 0; i < 2; ++i) {
      const int ofs = (w * 2 + i) * 512 + lane * 8;
      gll16(k_hi + tb + ofs, KhS + ofs);
      gll16(k_lo + tb + ofs, KlS + ofs);
      gll16(vimg + tb + ofs, VtS + ofs);
    }
    __syncthreads();

    // ---- S = Q K^T (3-term split precision) ----
    f32x4 S[2][2];
    #pragma unroll
    for (int rt = 0; rt < 2; ++rt)
      #pragma unroll
      for (int ct = 0; ct < 2; ++ct)
        #pragma unroll
        for (int r = 0; r < 4; ++r) S[rt][ct][r] = 0.f;
    #pragma unroll
    for (int kc = 0; kc < 4; ++kc) {
      const int o = kc * 1024 + quad * 8;
      const bf16x8 bh0 = *(const bf16x8*)&KhS[o + l15 * 32];
      const bf16x8 bh1 = *(const bf16x8*)&KhS[o + (16 + l15) * 32];
      const bf16x8 bl0 = *(const bf16x8*)&KlS[o + l15 * 32];
      const bf16x8 bl1 = *(const bf16x8*)&KlS[o + (16 + l15) * 32];
      #pragma unroll
      for (int rt = 0; rt < 2; ++rt) {
        S[rt][0] = mfma_bf16(Ql[rt][kc], bh0, S[rt][0]);
        S[rt][0] = mfma_bf16(Qh[rt][kc], bl0, S[rt][0]);
        S[rt][0] = mfma_bf16(Qh[rt][kc], bh0, S[rt][0]);
        S[rt][1] = mfma_bf16(Ql[rt][kc], bh1, S[rt][1]);
        S[rt][1] = mfma_bf16(Qh[rt][kc], bl1, S[rt][1]);
        S[rt][1] = mfma_bf16(Qh[rt][kc], bh1, S[rt][1]);
      }
    }

    // ---- online softmax, exp2 domain (scale pre-folded into q) ----
    #pragma unroll
    for (int rt = 0; rt < 2; ++rt) {
      #pragma unroll
      for (int r = 0; r < 4; ++r) {
        const float s0 = S[rt][0][r];
        const float s1 = S[rt][1][r];
        float mx = fmaxf(s0, s1);
        #pragma unroll
        for (int msk = 1; msk < 16; msk <<= 1) mx = fmaxf(mx, __shfl_xor(mx, msk));
        const float m_new = fmaxf(m_i[rt][r], mx);
        const float alpha = exp2f(m_i[rt][r] - m_new);
        m_i[rt][r] = m_new;
        const float p0 = exp2f(s0 - m_new);
        const float p1 = exp2f(s1 - m_new);
        float rs = p0 + p1;
        #pragma unroll
        for (int msk = 1; msk < 16; msk <<= 1) rs += __shfl_xor(rs, msk);
        l_i[rt][r] = l_i[rt][r] * alpha + rs;
        #pragma unroll
        for (int n = 0; n < 8; ++n) O[rt][n][r] *= alpha;
        const int prow = w * 32 + rt * 16 + quad * 4 + r;
        // truncation-pack to bf16: uniform relative bias cancels in O/l
        PS[prow * 32 + l15]      = (unsigned short)(__float_as_uint(p0) >> 16);
        PS[prow * 32 + 16 + l15] = (unsigned short)(__float_as_uint(p1) >> 16);
      }
    }
    __syncthreads();

    // ---- O += P V ----
    bf16x8 aP[2];
    #pragma unroll
    for (int rt = 0; rt < 2; ++rt)
      aP[rt] = *(const bf16x8*)&PS[(w * 32 + rt * 16 + l15) * 32 + quad * 8];
    #pragma unroll
    for (int n = 0; n < 8; ++n) {
      const bf16x8 bv = *(const bf16x8*)&VtS[(n * 16 + l15) * 32 + quad * 8];
      O[0][n] = mfma_bf16(aP[0], bv, O[0][n]);
      O[1][n] = mfma_bf16(aP[1], bv, O[1][n]);
    }
  }

  // ---- epilogue: xo = x + O / l ----
  const int b = bh >> 3, hh = bh & 7;
  #pragma unroll
  for (int rt = 0; rt < 2; ++rt) {
    #pragma unroll
    for (int r = 0; r < 4; ++r) {
      const float inv_l = 1.0f / l_i[rt][r];
      const int t = qt0 + w * 32 + rt * 16 + quad * 4 + r;
      const size_t xrow = ((size_t)(b * T_ + t)) * C_ + (size_t)hh * DH;
      #pragma unroll
      for (int n = 0; n < 8; ++n) {
        const int d = n * 16 + l15;
        xo[xrow + d] = x[xrow + d] + O[rt][n][r] * inv_l;
      }
    }
  }
}

// ---------------------------------------------------------------------------
// Workspace layout (MB offsets):
//   0-32    xo    f32 [M][C]
//   32-48   q_hi  bf16 [bh][t][d] (pre-scaled)   \
//   48-64   q_lo  bf16 [bh][t][d]                 \
//   64-80   k_hi  bf16 image [bh][64][4][32][32]   } ff1 aliases 32-96 after attn
//   80-96   k_lo  bf16 image                      /
//   96-112  vimg  bf16 image [bh][64][128][32]
//   112-128 h_hi  bf16 [M][C]
//   128-144 h_lo  bf16 [M][C]
//   144-152 w1t   bf16 [DFF][C]
//   152-160 w2t   bf16 [C][DFF]
//   160-166 wt_hi bf16 [3H][DH][C]
//   166-172 wt_lo bf16 [3H][DH][C]
// ---------------------------------------------------------------------------
extern "C" void kernel_launch(void* const* d_in, const int* in_sizes, int n_in,
                              void* d_out, int out_size, void* d_ws, size_t ws_size,
                              hipStream_t stream) {
  (void)in_sizes; (void)n_in; (void)out_size; (void)ws_size;
  const float* x     = (const float*)d_in[0];
  const float* wq    = (const float*)d_in[1];
  const float* wk    = (const float*)d_in[2];
  const float* wv    = (const float*)d_in[3];
  const float* w1    = (const float*)d_in[4];
  const float* b1    = (const float*)d_in[5];
  const float* w2    = (const float*)d_in[6];
  const float* b2    = (const float*)d_in[7];
  const float* ln1_g = (const float*)d_in[8];
  const float* ln1_b = (const float*)d_in[9];
  const float* ln2_g = (const float*)d_in[10];
  const float* ln2_b = (const float*)d_in[11];
  float* out = (float*)d_out;

  char* W = (char*)d_ws;
  float* xo = (float*)(W);
  unsigned short* q_hi  = (unsigned short*)(W + (32u  << 20));
  unsigned short* q_lo  = (unsigned short*)(W + (48u  << 20));
  unsigned short* k_hi  = (unsigned short*)(W + (64u  << 20));
  unsigned short* k_lo  = (unsigned short*)(W + (80u  << 20));
  unsigned short* vimg  = (unsigned short*)(W + (96u  << 20));
  unsigned short* ff1   = (unsigned short*)(W + (32u  << 20));   // aliases q/k
  unsigned short* h_hi  = (unsigned short*)(W + (112u << 20));
  unsigned short* h_lo  = (unsigned short*)(W + (128u << 20));
  unsigned short* w1t   = (unsigned short*)(W + (144u << 20));
  unsigned short* w2t   = (unsigned short*)(W + (152u << 20));
  unsigned short* wt_hi = (unsigned short*)(W + (160u << 20));
  unsigned short* wt_lo = (unsigned short*)(W + (166u << 20));

  cvt_t_kernel<<<dim3(DFF / 32, C_ / 32), 256, 0, stream>>>(w1, w1t, C_, DFF);
  cvt_t_kernel<<<dim3(C_ / 32, DFF / 32), 256, 0, stream>>>(w2, w2t, DFF, C_);
  cvt_qkv_kernel<<<dim3(DH / 32, C_ / 32, 24), 256, 0, stream>>>(wq, wk, wv, wt_hi, wt_lo);
  ln_kernel<<<M_, 256, 0, stream>>>(x, ln1_g, ln1_b, h_hi, h_lo);
  qkm_kernel<<<dim3(M_ / 128, 16), 256, 0, stream>>>(h_hi, h_lo, wt_hi, wt_lo,
                                                     q_hi, q_lo, k_hi, k_lo);
  vm_kernel<<<dim3(M_ / 128, H_), 256, 0, stream>>>(h_hi, wt_hi, vimg);
  attn_kernel<<<dim3(T_ / BQ, B_ * H_), 256, 0, stream>>>(q_hi, q_lo, k_hi, k_lo,
                                                          vimg, x, xo);
  ln_kernel<<<M_, 256, 0, stream>>>(xo, ln2_g, ln2_b, h_hi, h_lo);
  ff1_kernel<<<dim3(DFF / 128, M_ / 128), 256, 0, stream>>>(h_hi, w1t, b1, ff1);
  ff2_kernel<<<dim3(C_ / 128, M_ / 128), 256, 0, stream>>>(ff1, w2t, b2, xo, out);
}